// Round 13
// baseline (254.512 us; speedup 1.0000x reference)
//
#include <hip/hip_runtime.h>

#define HID 128
#define PTS 32
#define KP  136   // sB k-row stride in bf16 units (128 + 8 pad; rows 272B = 16B-aligned)
#define FRAGS_PER_W 2048           // 4 mw * 8 ks8 * 64 lanes
#define WS_ELEMS (FRAGS_PER_W * 8) // ushorts per (w, hi/lo) plane

typedef float v4f  __attribute__((ext_vector_type(4)));
typedef float v16f __attribute__((ext_vector_type(16)));
typedef short s8v  __attribute__((ext_vector_type(8)));         // 8 bf16 (MFMA A/B frag)

__device__ __forceinline__ unsigned short f2bf(float f) {       // RNE (prep only)
    unsigned u = __builtin_bit_cast(unsigned, f);
    u = (u + 0x7FFFu + ((u >> 16) & 1u)) >> 16;
    return (unsigned short)u;
}
__device__ __forceinline__ float bf2f(unsigned short h) {
    unsigned u = ((unsigned)h) << 16;
    return __builtin_bit_cast(float, u);
}

// --- packed fp32 -> 2x bf16 (RNE), 1 instr on gfx950 ---
#if __has_builtin(__builtin_amdgcn_cvt_pk_bf16_f32)
typedef __bf16 bf16x2 __attribute__((ext_vector_type(2)));
__device__ __forceinline__ unsigned pk2(float f0, float f1) {   // (bf(f1)<<16)|bf(f0)
    return __builtin_bit_cast(unsigned, __builtin_amdgcn_cvt_pk_bf16_f32(f0, f1));
}
#else
__device__ __forceinline__ unsigned pk2(float f0, float f1) {
    unsigned u0 = __builtin_bit_cast(unsigned, f0);
    unsigned u1 = __builtin_bit_cast(unsigned, f1);
    u0 += 0x7FFFu + ((u0 >> 16) & 1u);
    u1 += 0x7FFFu + ((u1 >> 16) & 1u);
    return __builtin_amdgcn_perm(u1, u0, 0x07060302u);
}
#endif
__device__ __forceinline__ uint2 pk4(const float* f) {
    uint2 h;
    h.x = pk2(f[0], f[1]);
    h.y = pk2(f[2], f[3]);
    return h;
}

// tanh(x) = 1 - 2/(exp(2x)+1); single mul + v_exp + v_rcp
__device__ __forceinline__ float fast_tanh(float x) {
#if __has_builtin(__builtin_amdgcn_exp2f)
    float e = __builtin_amdgcn_exp2f(x * 2.885390081777927f);   // 2*log2(e)
#else
    float e = __expf(2.0f * x);
#endif
    float r = __builtin_amdgcn_rcpf(e + 1.0f);
    return 1.0f - 2.0f * r;
}

// One-time: W1/W2 -> RNE-split bf16 A-fragments for 32x32x16, frag-linear in d_ws.
// A[m][k] = W[k][m]; m = mw*32 + (lane&31), k = ks8*16 + (lane>>5)*8 + i.
// frag idx r = mw*512 + ks8*64 + lane. Planes: [W1hi][W1lo][W2hi][W2lo].
__global__ __launch_bounds__(256) void prep_w_kernel(
    const float* __restrict__ W1, const float* __restrict__ W2,
    unsigned short* __restrict__ ws, float* __restrict__ out)
{
    if (blockIdx.x == 0 && threadIdx.x < 2) out[threadIdx.x] = 0.0f;
    const int t = blockIdx.x * 256 + threadIdx.x;   // 0..4095
    const int w = t >> 11;
    const int r = t & 2047;
    const int mw = r >> 9;
    const int ks8 = (r >> 6) & 7;
    const int lane = r & 63;
    const int m = mw * 32 + (lane & 31);
    const int kb = ks8 * 16 + (lane >> 5) * 8;
    const float* W = w ? W2 : W1;
    s8v hv, lv;
    #pragma unroll
    for (int i = 0; i < 8; ++i) {
        float f = W[(kb + i) * HID + m];
        unsigned short hh = f2bf(f);
        hv[i] = (short)hh;
        lv[i] = (short)f2bf(f - bf2f(hh));
    }
    *(s8v*)&ws[((size_t)(w * 2 + 0) * FRAGS_PER_W + r) * 8] = hv;
    *(s8v*)&ws[((size_t)(w * 2 + 1) * FRAGS_PER_W + r) * 8] = lv;
}

// Round-12 structure (proven: 152us, VGPR 56 + 64 AGPR = 120/128 budget) plus:
// (a) boundary blocks run ONLY the value channel end-to-end (nt=0): -75% of
//     their MFMA/LDS; (b) readout fused into the L=1 epilogue (chain + W3 dot
//     in registers, cross-wave combine via 128-float sPart): deletes the rc-row
//     pack/stores, readout LDS reads, and one barrier (4 barriers total).
// One block = 32 points. Wave = m-tile mw (32 j) x all n. C/D (m101, verified):
// col=lane&31 (=p), row=(reg&3)+8*(reg>>2)+4*(lane>>5) (=j offset).
// 2-product split-bf16 (W=hi+lo exact to 2^-18); activations RNE bf16 in LDS.
__global__ __launch_bounds__(256, 4) void pinn_mfma_kernel(
    const float* __restrict__ xy_int, const float* __restrict__ f_t,
    const float* __restrict__ xy_bd, const float* __restrict__ g_t,
    const float* __restrict__ W0, const float* __restrict__ b0,
    const float* __restrict__ b1, const float* __restrict__ b2,
    const float* __restrict__ W3, const float* __restrict__ b3,
    const unsigned short* __restrict__ ws, float* __restrict__ out,
    int gi, float scale_int, float scale_bd)
{
    extern __shared__ char smem_raw[];
    unsigned short* sBh = (unsigned short*)smem_raw;     // [4*32][KP] bf16 (RNE)
    float* sPart = (float*)(sBh + 4 * 32 * KP);          // [128] per-(mw,p) partials

    const bool is_bd = (int)blockIdx.x >= gi;
    const float* __restrict__ xy  = is_bd ? xy_bd : xy_int;
    const float* __restrict__ tgt = is_bd ? g_t : f_t;
    const int pbase = (is_bd ? ((int)blockIdx.x - gi) : (int)blockIdx.x) * PTS;

    const int tid  = threadIdx.x;
    const int lane = tid & 63;
    const int mw   = tid >> 6;      // wave = m-tile (32 j-rows)
    const int l31  = lane & 31;
    const int kh   = lane >> 5;     // k-half of frag / +4*kh j-offset in C

    // ---- layer 0: 2 -> 128, VALU, RNE-bf16 store into sB ----
    {
        const int tj = tid & 31, tp = tid >> 5;
        const int j0 = tj * 4, p0 = tp * 4;
        float wx[4], wy[4], bb[4];
        #pragma unroll
        for (int jj = 0; jj < 4; ++jj) {
            wx[jj] = W0[j0 + jj];
            wy[jj] = W0[HID + j0 + jj];
            bb[jj] = b0[j0 + jj];
        }
        #pragma unroll
        for (int pp = 0; pp < 4; ++pp) {
            const int p = p0 + pp;
            const float2 t2 = ((const float2*)xy)[pbase + p];
            float chv[4][4];                    // [c][jj]
            #pragma unroll
            for (int jj = 0; jj < 4; ++jj) {
                float z = fmaf(t2.x, wx[jj], fmaf(t2.y, wy[jj], bb[jj]));
                float a = fast_tanh(z);
                chv[0][jj] = a;
                if (!is_bd) {
                    float t = fmaf(-a, a, 1.0f);
                    float s2 = fmaf(wx[jj], wx[jj], wy[jj] * wy[jj]);
                    chv[1][jj] = t * wx[jj];
                    chv[2][jj] = t * wy[jj];
                    chv[3][jj] = -2.0f * a * t * s2;    // z_lap = 0 at layer 0
                }
            }
            *(uint2*)&sBh[(0 * 32 + p) * KP + j0] = pk4(chv[0]);
            if (!is_bd) {
                #pragma unroll
                for (int c = 1; c < 4; ++c)
                    *(uint2*)&sBh[(c * 32 + p) * KP + j0] = pk4(chv[c]);
            }
        }
    }
    __syncthreads();

    v16f acc[4];    // [ntile == channel]; boundary uses acc[0] only

    #pragma unroll
    for (int L = 0; L < 2; ++L) {
        const unsigned short* wshi = ws + (size_t)L * 2 * WS_ELEMS;
        const unsigned short* wslo = wshi + WS_ELEMS;

        // stage = K32 = 2 ks8 sub-frags; double-buffered: 8 s8v = 32 VGPR
        s8v whi[2][2], wlo[2][2];
        #pragma unroll
        for (int h = 0; h < 2; ++h) {
            const int idx = mw * 512 + h * 64 + lane;         // stage 0
            whi[0][h] = *(const s8v*)&wshi[(size_t)idx * 8];
            wlo[0][h] = *(const s8v*)&wslo[(size_t)idx * 8];
        }

        #pragma unroll
        for (int nt = 0; nt < 4; ++nt) acc[nt] = (v16f)0.0f;

        #pragma unroll
        for (int s = 0; s < 4; ++s) {
            const int cur = s & 1, nxt = cur ^ 1;
            if (s < 3) {    // prefetch next stage from L2 while MFMAs run
                #pragma unroll
                for (int h = 0; h < 2; ++h) {
                    const int idx = mw * 512 + ((s + 1) * 2 + h) * 64 + lane;
                    whi[nxt][h] = *(const s8v*)&wshi[(size_t)idx * 8];
                    wlo[nxt][h] = *(const s8v*)&wslo[(size_t)idx * 8];
                }
            }
            #pragma unroll
            for (int h = 0; h < 2; ++h) {
                const int koff = (s * 2 + h) * 16 + kh * 8;   // B: k=(lane>>5)*8+i
                if (is_bd) {        // uniform: value channel only
                    s8v bh = *(const s8v*)&sBh[l31 * KP + koff];
                    acc[0] = __builtin_amdgcn_mfma_f32_32x32x16_bf16(
                        whi[cur][h], bh, acc[0], 0, 0, 0);
                    acc[0] = __builtin_amdgcn_mfma_f32_32x32x16_bf16(
                        wlo[cur][h], bh, acc[0], 0, 0, 0);
                } else {
                    #pragma unroll
                    for (int nt = 0; nt < 4; ++nt) {
                        s8v bh = *(const s8v*)&sBh[(nt * 32 + l31) * KP + koff];
                        acc[nt] = __builtin_amdgcn_mfma_f32_32x32x16_bf16(
                            whi[cur][h], bh, acc[nt], 0, 0, 0);
                        acc[nt] = __builtin_amdgcn_mfma_f32_32x32x16_bf16(
                            wlo[cur][h], bh, acc[nt], 0, 0, 0);
                    }
                }
            }
        }

        if (L == 0) {
            __syncthreads();        // all waves done reading sB
            // epilogue L0: channels -> sB (boundary: value only)
            #pragma unroll
            for (int g = 0; g < 4; ++g) {       // j = j0g + (reg&3)
                const int j0g = mw * 32 + 8 * g + 4 * kh;
                const v4f bb = *(const v4f*)&b1[j0g];
                float chv[4][4];                // [c][r]
                #pragma unroll
                for (int r = 0; r < 4; ++r) {
                    float z = acc[0][g * 4 + r] + bb[r];
                    float a = fast_tanh(z);
                    chv[0][r] = a;
                    if (!is_bd) {
                        float t = fmaf(-a, a, 1.0f);
                        float zx = acc[1][g * 4 + r], zy = acc[2][g * 4 + r],
                              zl = acc[3][g * 4 + r];
                        float s2 = fmaf(zx, zx, zy * zy);
                        chv[1][r] = t * zx;
                        chv[2][r] = t * zy;
                        chv[3][r] = fmaf(t, zl, -2.0f * a * t * s2);
                    }
                }
                *(uint2*)&sBh[(0 * 32 + l31) * KP + j0g] = pk4(chv[0]);
                if (!is_bd) {
                    #pragma unroll
                    for (int c = 1; c < 4; ++c)
                        *(uint2*)&sBh[(c * 32 + l31) * KP + j0g] = pk4(chv[c]);
                }
            }
            __syncthreads();
        }
    }

    // ---- fused readout on L=1 acc: chain + W3 dot in registers ----
    // (writes only sPart -- sB still being read by other waves is untouched)
    {
        float part = 0.0f;
        #pragma unroll
        for (int g = 0; g < 4; ++g) {
            const int j0g = mw * 32 + 8 * g + 4 * kh;
            const v4f bb = *(const v4f*)&b2[j0g];
            const v4f w3 = *(const v4f*)&W3[j0g];
            #pragma unroll
            for (int r = 0; r < 4; ++r) {
                float z = acc[0][g * 4 + r] + bb[r];
                float a = fast_tanh(z);
                float v;
                if (is_bd) {
                    v = a;                              // pred = a . W3
                } else {
                    float t = fmaf(-a, a, 1.0f);
                    float zx = acc[1][g * 4 + r], zy = acc[2][g * 4 + r],
                          zl = acc[3][g * 4 + r];
                    float s2 = fmaf(zx, zx, zy * zy);
                    v = t * fmaf(-2.0f * a, s2, zl);    // pred = lap . W3
                }
                part = fmaf(v, w3[r], part);
            }
        }
        part += __shfl_xor(part, 32, 64);   // combine the two kh halves
        if (kh == 0) sPart[mw * 32 + l31] = part;
        __syncthreads();
        if (mw == 0) {                      // wave 0: combine 4 m-tiles per point
            const int p = l31;
            float pred = (sPart[p] + sPart[32 + p]) + (sPart[64 + p] + sPart[96 + p])
                       + (is_bd ? b3[0] : 0.0f);        // lap kills b3
            float d = pred - tgt[pbase + p];
            float sq = (kh == 0) ? d * d : 0.0f;
            sq += __shfl_xor(sq, 1, 64);
            sq += __shfl_xor(sq, 2, 64);
            sq += __shfl_xor(sq, 4, 64);
            sq += __shfl_xor(sq, 8, 64);
            sq += __shfl_xor(sq, 16, 64);
            sq += __shfl_xor(sq, 32, 64);
            if (lane == 0)
                atomicAdd(out + (is_bd ? 0 : 1),
                          sq * (is_bd ? scale_bd : scale_int));
        }
    }
}

extern "C" void kernel_launch(void* const* d_in, const int* in_sizes, int n_in,
                              void* d_out, int out_size, void* d_ws, size_t ws_size,
                              hipStream_t stream) {
    const float* xy_int = (const float*)d_in[0];
    const float* f      = (const float*)d_in[1];
    const float* xy_bd  = (const float*)d_in[2];
    const float* g      = (const float*)d_in[3];
    const float* W0 = (const float*)d_in[4];
    const float* b0 = (const float*)d_in[5];
    const float* W1 = (const float*)d_in[6];
    const float* b1 = (const float*)d_in[7];
    const float* W2 = (const float*)d_in[8];
    const float* b2 = (const float*)d_in[9];
    const float* W3 = (const float*)d_in[10];
    const float* b3 = (const float*)d_in[11];
    float* out = (float*)d_out;
    unsigned short* ws = (unsigned short*)d_ws;   // needs 256 KB

    const int n_int = in_sizes[0] / 2;   // 262144
    const int n_bd  = in_sizes[2] / 2;   // 16384

    prep_w_kernel<<<16, 256, 0, stream>>>(W1, W2, ws, out);

    const int smem = (4 * 32 * KP) * 2 + 128 * 4;  // 35,328 B -> 4 blocks/CU
    const int gi = n_int / PTS;
    const int gb = n_bd / PTS;

    pinn_mfma_kernel<<<gi + gb, 256, smem, stream>>>(
        xy_int, f, xy_bd, g, W0, b0, b1, b2, W3, b3, ws, out,
        gi, 0.5f / (float)n_int, 0.5f / (float)n_bd);
}

// Round 14
// 214.639 us; speedup vs baseline: 1.1858x; 1.1858x over previous
//
#include <hip/hip_runtime.h>

#define HID 128
#define PTS 32
#define KP  136   // sB k-row stride in bf16 units (128 + 8 pad; rows 272B = 16B-aligned)
#define FRAGS_PER_W 2048           // 4 mw * 8 ks8 * 64 lanes
#define WS_ELEMS (FRAGS_PER_W * 8) // ushorts per (w, hi/lo) plane

typedef float v4f  __attribute__((ext_vector_type(4)));
typedef float v16f __attribute__((ext_vector_type(16)));
typedef short s8v  __attribute__((ext_vector_type(8)));         // 8 bf16 (MFMA A/B frag)

__device__ __forceinline__ unsigned short f2bf(float f) {       // RNE (prep only)
    unsigned u = __builtin_bit_cast(unsigned, f);
    u = (u + 0x7FFFu + ((u >> 16) & 1u)) >> 16;
    return (unsigned short)u;
}
__device__ __forceinline__ float bf2f(unsigned short h) {
    unsigned u = ((unsigned)h) << 16;
    return __builtin_bit_cast(float, u);
}

// --- packed fp32 -> 2x bf16 (RNE), 1 instr on gfx950 ---
#if __has_builtin(__builtin_amdgcn_cvt_pk_bf16_f32)
typedef __bf16 bf16x2 __attribute__((ext_vector_type(2)));
__device__ __forceinline__ unsigned pk2(float f0, float f1) {   // (bf(f1)<<16)|bf(f0)
    return __builtin_bit_cast(unsigned, __builtin_amdgcn_cvt_pk_bf16_f32(f0, f1));
}
#else
__device__ __forceinline__ unsigned pk2(float f0, float f1) {
    unsigned u0 = __builtin_bit_cast(unsigned, f0);
    unsigned u1 = __builtin_bit_cast(unsigned, f1);
    u0 += 0x7FFFu + ((u0 >> 16) & 1u);
    u1 += 0x7FFFu + ((u1 >> 16) & 1u);
    return __builtin_amdgcn_perm(u1, u0, 0x07060302u);
}
#endif
__device__ __forceinline__ uint2 pk4(const float* f) {
    uint2 h;
    h.x = pk2(f[0], f[1]);
    h.y = pk2(f[2], f[3]);
    return h;
}

// tanh(x) = 1 - 2/(exp(2x)+1); single mul + v_exp + v_rcp
__device__ __forceinline__ float fast_tanh(float x) {
#if __has_builtin(__builtin_amdgcn_exp2f)
    float e = __builtin_amdgcn_exp2f(x * 2.885390081777927f);   // 2*log2(e)
#else
    float e = __expf(2.0f * x);
#endif
    float r = __builtin_amdgcn_rcpf(e + 1.0f);
    return 1.0f - 2.0f * r;
}

// One-time: W1/W2 -> RNE-split bf16 A-fragments for 32x32x16, frag-linear in d_ws.
// A[m][k] = W[k][m]; m = mw*32 + (lane&31), k = ks8*16 + (lane>>5)*8 + i.
// frag idx r = mw*512 + ks8*64 + lane. Planes: [W1hi][W1lo][W2hi][W2lo].
__global__ __launch_bounds__(256) void prep_w_kernel(
    const float* __restrict__ W1, const float* __restrict__ W2,
    unsigned short* __restrict__ ws, float* __restrict__ out)
{
    if (blockIdx.x == 0 && threadIdx.x < 2) out[threadIdx.x] = 0.0f;
    const int t = blockIdx.x * 256 + threadIdx.x;   // 0..4095
    const int w = t >> 11;
    const int r = t & 2047;
    const int mw = r >> 9;
    const int ks8 = (r >> 6) & 7;
    const int lane = r & 63;
    const int m = mw * 32 + (lane & 31);
    const int kb = ks8 * 16 + (lane >> 5) * 8;
    const float* W = w ? W2 : W1;
    s8v hv, lv;
    #pragma unroll
    for (int i = 0; i < 8; ++i) {
        float f = W[(kb + i) * HID + m];
        unsigned short hh = f2bf(f);
        hv[i] = (short)hh;
        lv[i] = (short)f2bf(f - bf2f(hh));
    }
    *(s8v*)&ws[((size_t)(w * 2 + 0) * FRAGS_PER_W + r) * 8] = hv;
    *(s8v*)&ws[((size_t)(w * 2 + 1) * FRAGS_PER_W + r) * 8] = lv;
}

// Round-12 body, templated on channel count. NC=4: interior (lap readout, ch
// 0=val,1=dx,2=dy,3=lap). NC=1: boundary (value only, -75% MFMA/LDS/packing).
// LESSON (r13): uniform branches must be COARSE-GRAIN -- one diamond at kernel
// entry; in-loop is_bd diamonds broke SROA at the 120/128-reg budget (180 MB spill).
// Wave = m-tile mw (32 j) x all n-tiles (==channels). C/D (m101, verified):
// col=lane&31 (=p), row=(reg&3)+8*(reg>>2)+4*(lane>>5) (=j offset).
// 2-product split-bf16 (W=hi+lo exact to 2^-18); activations RNE bf16 in LDS.
template <int NC>
__device__ __forceinline__ void run_pinn(
    const float* __restrict__ xy, const float* __restrict__ tgt,
    const float* __restrict__ W0, const float* __restrict__ b0,
    const float* __restrict__ b1, const float* __restrict__ b2,
    const float* __restrict__ W3, const float* __restrict__ b3,
    const unsigned short* __restrict__ ws, float* __restrict__ out_slot,
    float scale, int pbase, unsigned short* sBh, float* sRed)
{
    constexpr int RC = (NC == 4) ? 3 : 0;   // readout channel
    const int tid  = threadIdx.x;
    const int lane = tid & 63;
    const int mw   = tid >> 6;      // wave = m-tile (32 j-rows)
    const int l31  = lane & 31;
    const int kh   = lane >> 5;     // k-half of frag / +4*kh j-offset in C

    // ---- layer 0: 2 -> 128, VALU, RNE-bf16 store into sB ----
    {
        const int tj = tid & 31, tp = tid >> 5;
        const int j0 = tj * 4, p0 = tp * 4;
        float wx[4], wy[4], bb[4];
        #pragma unroll
        for (int jj = 0; jj < 4; ++jj) {
            wx[jj] = W0[j0 + jj];
            wy[jj] = W0[HID + j0 + jj];
            bb[jj] = b0[j0 + jj];
        }
        #pragma unroll
        for (int pp = 0; pp < 4; ++pp) {
            const int p = p0 + pp;
            const float2 t2 = ((const float2*)xy)[pbase + p];
            float chv[NC][4];                   // [c][jj]
            #pragma unroll
            for (int jj = 0; jj < 4; ++jj) {
                float z = fmaf(t2.x, wx[jj], fmaf(t2.y, wy[jj], bb[jj]));
                float a = fast_tanh(z);
                chv[0][jj] = a;
                if (NC == 4) {
                    float t = fmaf(-a, a, 1.0f);
                    float s2 = fmaf(wx[jj], wx[jj], wy[jj] * wy[jj]);
                    chv[1][jj] = t * wx[jj];
                    chv[2][jj] = t * wy[jj];
                    chv[3][jj] = -2.0f * a * t * s2;    // z_lap = 0 at layer 0
                }
            }
            #pragma unroll
            for (int c = 0; c < NC; ++c) {
                const int row = (c * 32 + p) * KP + j0;
                *(uint2*)&sBh[row] = pk4(chv[c]);
            }
        }
    }
    __syncthreads();

    // ---- hidden layers: D = (Whi+Wlo)(A-op 32x32) x Act(B-op), 2-product ----
    #pragma unroll
    for (int L = 0; L < 2; ++L) {
        const unsigned short* wshi = ws + (size_t)L * 2 * WS_ELEMS;
        const unsigned short* wslo = wshi + WS_ELEMS;

        // stage = K32 = 2 ks8 sub-frags; double-buffered: 8 s8v = 32 VGPR
        s8v whi[2][2], wlo[2][2];
        #pragma unroll
        for (int h = 0; h < 2; ++h) {
            const int idx = mw * 512 + h * 64 + lane;         // stage 0
            whi[0][h] = *(const s8v*)&wshi[(size_t)idx * 8];
            wlo[0][h] = *(const s8v*)&wslo[(size_t)idx * 8];
        }

        v16f acc[NC] = {};  // [ntile == channel]

        #pragma unroll
        for (int s = 0; s < 4; ++s) {
            const int cur = s & 1, nxt = cur ^ 1;
            if (s < 3) {    // prefetch next stage from L2 while MFMAs run
                #pragma unroll
                for (int h = 0; h < 2; ++h) {
                    const int idx = mw * 512 + ((s + 1) * 2 + h) * 64 + lane;
                    whi[nxt][h] = *(const s8v*)&wshi[(size_t)idx * 8];
                    wlo[nxt][h] = *(const s8v*)&wslo[(size_t)idx * 8];
                }
            }
            #pragma unroll
            for (int h = 0; h < 2; ++h) {
                const int koff = (s * 2 + h) * 16 + kh * 8;   // B: k=(lane>>5)*8+i
                #pragma unroll
                for (int nt = 0; nt < NC; ++nt) {
                    s8v bh = *(const s8v*)&sBh[(nt * 32 + l31) * KP + koff];
                    acc[nt] = __builtin_amdgcn_mfma_f32_32x32x16_bf16(
                        whi[cur][h], bh, acc[nt], 0, 0, 0);
                    acc[nt] = __builtin_amdgcn_mfma_f32_32x32x16_bf16(
                        wlo[cur][h], bh, acc[nt], 0, 0, 0);
                }
            }
        }
        __syncthreads();            // all waves done reading sB

        const float* __restrict__ bptr = (L == 0) ? b1 : b2;
        #pragma unroll
        for (int g = 0; g < 4; ++g) {       // reg-groups: j = j0g + (r&3)
            const int j0g = mw * 32 + 8 * g + 4 * kh;
            const v4f bb = *(const v4f*)&bptr[j0g];
            float chv[NC][4];               // [c][r]
            #pragma unroll
            for (int r = 0; r < 4; ++r) {
                float z = acc[0][g * 4 + r] + bb[r];
                float a = fast_tanh(z);
                chv[0][r] = a;
                if (NC == 4) {
                    float t = fmaf(-a, a, 1.0f);
                    float zx = acc[1][g * 4 + r], zy = acc[2][g * 4 + r],
                          zl = acc[3][g * 4 + r];
                    float s2 = fmaf(zx, zx, zy * zy);
                    chv[1][r] = t * zx;
                    chv[2][r] = t * zy;
                    chv[3][r] = fmaf(t, zl, -2.0f * a * t * s2);
                }
            }
            #pragma unroll
            for (int c = 0; c < NC; ++c) {
                if (L == 1 && c != RC) continue;    // last layer: readout row only
                const int row = (c * 32 + l31) * KP + j0g;
                *(uint2*)&sBh[row] = pk4(chv[c]);
            }
        }
        __syncthreads();
    }

    // ---- readout: dot with W3 over k, 8 lanes per point ----
    {
        const int p  = tid >> 3;
        const int i  = tid & 7;
        const int k0 = i * 16;
        const int row = (RC * 32 + p) * KP + k0;
        float r = 0.0f;
        #pragma unroll
        for (int h = 0; h < 2; ++h) {
            s8v vh = *(const s8v*)&sBh[row + h * 8];
            #pragma unroll
            for (int t = 0; t < 8; ++t)
                r = fmaf(bf2f((unsigned short)vh[t]), W3[k0 + h * 8 + t], r);
        }
        r += __shfl_xor(r, 1, 64);
        r += __shfl_xor(r, 2, 64);
        r += __shfl_xor(r, 4, 64);
        if (i == 0) {
            float d = r + ((NC == 1) ? b3[0] : 0.0f) - tgt[pbase + p]; // lap kills b3
            sRed[p] = d * d;
        }
    }
    __syncthreads();
    if (tid == 0) {
        float s = 0.0f;
        #pragma unroll
        for (int p = 0; p < PTS; ++p) s += sRed[p];
        atomicAdd(out_slot, s * scale);
    }
}

// Fused interior+boundary: ONE uniform branch at entry (coarse-grain diamond),
// each side a clean straight-line template instantiation.
__global__ __launch_bounds__(256, 4) void pinn_mfma_kernel(
    const float* __restrict__ xy_int, const float* __restrict__ f_t,
    const float* __restrict__ xy_bd, const float* __restrict__ g_t,
    const float* __restrict__ W0, const float* __restrict__ b0,
    const float* __restrict__ b1, const float* __restrict__ b2,
    const float* __restrict__ W3, const float* __restrict__ b3,
    const unsigned short* __restrict__ ws, float* __restrict__ out,
    int gi, float scale_int, float scale_bd)
{
    extern __shared__ char smem_raw[];
    unsigned short* sBh = (unsigned short*)smem_raw;     // [4*32][KP] bf16 (RNE)
    float* sRed = (float*)(sBh + 4 * 32 * KP);           // [PTS]

    const int b = (int)blockIdx.x;
    if (b >= gi)
        run_pinn<1>(xy_bd, g_t, W0, b0, b1, b2, W3, b3, ws,
                    out + 0, scale_bd, (b - gi) * PTS, sBh, sRed);
    else
        run_pinn<4>(xy_int, f_t, W0, b0, b1, b2, W3, b3, ws,
                    out + 1, scale_int, b * PTS, sBh, sRed);
}

extern "C" void kernel_launch(void* const* d_in, const int* in_sizes, int n_in,
                              void* d_out, int out_size, void* d_ws, size_t ws_size,
                              hipStream_t stream) {
    const float* xy_int = (const float*)d_in[0];
    const float* f      = (const float*)d_in[1];
    const float* xy_bd  = (const float*)d_in[2];
    const float* g      = (const float*)d_in[3];
    const float* W0 = (const float*)d_in[4];
    const float* b0 = (const float*)d_in[5];
    const float* W1 = (const float*)d_in[6];
    const float* b1 = (const float*)d_in[7];
    const float* W2 = (const float*)d_in[8];
    const float* b2 = (const float*)d_in[9];
    const float* W3 = (const float*)d_in[10];
    const float* b3 = (const float*)d_in[11];
    float* out = (float*)d_out;
    unsigned short* ws = (unsigned short*)d_ws;   // needs 256 KB

    const int n_int = in_sizes[0] / 2;   // 262144
    const int n_bd  = in_sizes[2] / 2;   // 16384

    prep_w_kernel<<<16, 256, 0, stream>>>(W1, W2, ws, out);

    const int smem = (4 * 32 * KP) * 2 + PTS * 4;  // 34,944 B -> 4 blocks/CU
    const int gi = n_int / PTS;
    const int gb = n_bd / PTS;

    pinn_mfma_kernel<<<gi + gb, 256, smem, stream>>>(
        xy_int, f, xy_bd, g, W0, b0, b1, b2, W3, b3, ws, out,
        gi, 0.5f / (float)n_int, 0.5f / (float)n_bd);
}

// Round 15
// 214.123 us; speedup vs baseline: 1.1886x; 1.0024x over previous
//
#include <hip/hip_runtime.h>

#define HID 128
#define PTS 32
#define KP  136   // sB k-row stride in bf16 units (128 + 8 pad; rows 272B = 16B-aligned)
#define FRAGS_PER_W 2048           // 4 mw * 8 ks8 * 64 lanes
#define WS_ELEMS (FRAGS_PER_W * 8) // ushorts per (w, hi/lo) plane

typedef float v4f  __attribute__((ext_vector_type(4)));
typedef float v16f __attribute__((ext_vector_type(16)));
typedef short s8v  __attribute__((ext_vector_type(8)));         // 8 bf16 (MFMA A/B frag)

__device__ __forceinline__ unsigned short f2bf(float f) {       // RNE (prep only)
    unsigned u = __builtin_bit_cast(unsigned, f);
    u = (u + 0x7FFFu + ((u >> 16) & 1u)) >> 16;
    return (unsigned short)u;
}
__device__ __forceinline__ float bf2f(unsigned short h) {
    unsigned u = ((unsigned)h) << 16;
    return __builtin_bit_cast(float, u);
}

// --- packed fp32 -> 2x bf16 (RNE), 1 instr on gfx950 ---
#if __has_builtin(__builtin_amdgcn_cvt_pk_bf16_f32)
typedef __bf16 bf16x2 __attribute__((ext_vector_type(2)));
__device__ __forceinline__ unsigned pk2(float f0, float f1) {   // (bf(f1)<<16)|bf(f0)
    return __builtin_bit_cast(unsigned, __builtin_amdgcn_cvt_pk_bf16_f32(f0, f1));
}
#else
__device__ __forceinline__ unsigned pk2(float f0, float f1) {
    unsigned u0 = __builtin_bit_cast(unsigned, f0);
    unsigned u1 = __builtin_bit_cast(unsigned, f1);
    u0 += 0x7FFFu + ((u0 >> 16) & 1u);
    u1 += 0x7FFFu + ((u1 >> 16) & 1u);
    return __builtin_amdgcn_perm(u1, u0, 0x07060302u);
}
#endif
__device__ __forceinline__ uint2 pk4(const float* f) {
    uint2 h;
    h.x = pk2(f[0], f[1]);
    h.y = pk2(f[2], f[3]);
    return h;
}

// tanh(x) = 1 - 2/(exp(2x)+1); single mul + v_exp + v_rcp
__device__ __forceinline__ float fast_tanh(float x) {
#if __has_builtin(__builtin_amdgcn_exp2f)
    float e = __builtin_amdgcn_exp2f(x * 2.885390081777927f);   // 2*log2(e)
#else
    float e = __expf(2.0f * x);
#endif
    float r = __builtin_amdgcn_rcpf(e + 1.0f);
    return 1.0f - 2.0f * r;
}

// One-time: W1/W2 -> RNE-split bf16 A-fragments for 32x32x16, frag-linear in d_ws.
// A[m][k] = W[k][m]; m = mw*32 + (lane&31), k = ks8*16 + (lane>>5)*8 + i.
// frag idx r = mw*512 + ks8*64 + lane. Planes: [W1hi][W1lo][W2hi][W2lo].
__global__ __launch_bounds__(256) void prep_w_kernel(
    const float* __restrict__ W1, const float* __restrict__ W2,
    unsigned short* __restrict__ ws, float* __restrict__ out)
{
    if (blockIdx.x == 0 && threadIdx.x < 2) out[threadIdx.x] = 0.0f;
    const int t = blockIdx.x * 256 + threadIdx.x;   // 0..4095
    const int w = t >> 11;
    const int r = t & 2047;
    const int mw = r >> 9;
    const int ks8 = (r >> 6) & 7;
    const int lane = r & 63;
    const int m = mw * 32 + (lane & 31);
    const int kb = ks8 * 16 + (lane >> 5) * 8;
    const float* W = w ? W2 : W1;
    s8v hv, lv;
    #pragma unroll
    for (int i = 0; i < 8; ++i) {
        float f = W[(kb + i) * HID + m];
        unsigned short hh = f2bf(f);
        hv[i] = (short)hh;
        lv[i] = (short)f2bf(f - bf2f(hh));
    }
    *(s8v*)&ws[((size_t)(w * 2 + 0) * FRAGS_PER_W + r) * 8] = hv;
    *(s8v*)&ws[((size_t)(w * 2 + 1) * FRAGS_PER_W + r) * 8] = lv;
}

// Round-14 body (proven 146.7us, VGPR 64, no spill) + readout fused into the
// L=1 epilogue: at that point the W double-buffer is dead, so the fused chain
// (tanh + lap + W3-dot in registers) fits the 120/128-reg budget. Deletes the
// L=1 pack/stores, the readout LDS round-trip, one barrier, and the serial sum.
// LESSON (r13): uniform branches COARSE-GRAIN only (template dispatch at entry).
// NC=4: interior (lap readout). NC=1: boundary (value only, -75% MFMA/LDS).
// Wave = m-tile mw (32 j) x all n-tiles (==channels). C/D (m101, verified):
// col=lane&31 (=p), row=(reg&3)+8*(reg>>2)+4*(lane>>5) (=j offset).
// 2-product split-bf16 (W=hi+lo exact to 2^-18); activations RNE bf16 in LDS.
template <int NC>
__device__ __forceinline__ void run_pinn(
    const float* __restrict__ xy, const float* __restrict__ tgt,
    const float* __restrict__ W0, const float* __restrict__ b0,
    const float* __restrict__ b1, const float* __restrict__ b2,
    const float* __restrict__ W3, const float* __restrict__ b3,
    const unsigned short* __restrict__ ws, float* __restrict__ out_slot,
    float scale, int pbase, unsigned short* sBh, float* sPart)
{
    const int tid  = threadIdx.x;
    const int lane = tid & 63;
    const int mw   = tid >> 6;      // wave = m-tile (32 j-rows)
    const int l31  = lane & 31;
    const int kh   = lane >> 5;     // k-half of frag / +4*kh j-offset in C

    // ---- layer 0: 2 -> 128, VALU, RNE-bf16 store into sB ----
    {
        const int tj = tid & 31, tp = tid >> 5;
        const int j0 = tj * 4, p0 = tp * 4;
        float wx[4], wy[4], bb[4];
        #pragma unroll
        for (int jj = 0; jj < 4; ++jj) {
            wx[jj] = W0[j0 + jj];
            wy[jj] = W0[HID + j0 + jj];
            bb[jj] = b0[j0 + jj];
        }
        #pragma unroll
        for (int pp = 0; pp < 4; ++pp) {
            const int p = p0 + pp;
            const float2 t2 = ((const float2*)xy)[pbase + p];
            float chv[NC][4];                   // [c][jj]
            #pragma unroll
            for (int jj = 0; jj < 4; ++jj) {
                float z = fmaf(t2.x, wx[jj], fmaf(t2.y, wy[jj], bb[jj]));
                float a = fast_tanh(z);
                chv[0][jj] = a;
                if (NC == 4) {
                    float t = fmaf(-a, a, 1.0f);
                    float s2 = fmaf(wx[jj], wx[jj], wy[jj] * wy[jj]);
                    chv[1][jj] = t * wx[jj];
                    chv[2][jj] = t * wy[jj];
                    chv[3][jj] = -2.0f * a * t * s2;    // z_lap = 0 at layer 0
                }
            }
            #pragma unroll
            for (int c = 0; c < NC; ++c) {
                const int row = (c * 32 + p) * KP + j0;
                *(uint2*)&sBh[row] = pk4(chv[c]);
            }
        }
    }
    __syncthreads();

    v16f acc[NC];   // [ntile == channel]

    // ---- hidden layers: D = (Whi+Wlo)(A-op 32x32) x Act(B-op), 2-product ----
    #pragma unroll
    for (int L = 0; L < 2; ++L) {
        const unsigned short* wshi = ws + (size_t)L * 2 * WS_ELEMS;
        const unsigned short* wslo = wshi + WS_ELEMS;

        // stage = K32 = 2 ks8 sub-frags; double-buffered: 8 s8v = 32 VGPR
        s8v whi[2][2], wlo[2][2];
        #pragma unroll
        for (int h = 0; h < 2; ++h) {
            const int idx = mw * 512 + h * 64 + lane;         // stage 0
            whi[0][h] = *(const s8v*)&wshi[(size_t)idx * 8];
            wlo[0][h] = *(const s8v*)&wslo[(size_t)idx * 8];
        }

        #pragma unroll
        for (int nt = 0; nt < NC; ++nt) acc[nt] = (v16f)0.0f;

        #pragma unroll
        for (int s = 0; s < 4; ++s) {
            const int cur = s & 1, nxt = cur ^ 1;
            if (s < 3) {    // prefetch next stage from L2 while MFMAs run
                #pragma unroll
                for (int h = 0; h < 2; ++h) {
                    const int idx = mw * 512 + ((s + 1) * 2 + h) * 64 + lane;
                    whi[nxt][h] = *(const s8v*)&wshi[(size_t)idx * 8];
                    wlo[nxt][h] = *(const s8v*)&wslo[(size_t)idx * 8];
                }
            }
            #pragma unroll
            for (int h = 0; h < 2; ++h) {
                const int koff = (s * 2 + h) * 16 + kh * 8;   // B: k=(lane>>5)*8+i
                #pragma unroll
                for (int nt = 0; nt < NC; ++nt) {
                    s8v bh = *(const s8v*)&sBh[(nt * 32 + l31) * KP + koff];
                    acc[nt] = __builtin_amdgcn_mfma_f32_32x32x16_bf16(
                        whi[cur][h], bh, acc[nt], 0, 0, 0);
                    acc[nt] = __builtin_amdgcn_mfma_f32_32x32x16_bf16(
                        wlo[cur][h], bh, acc[nt], 0, 0, 0);
                }
            }
        }

        if (L == 0) {
            __syncthreads();        // all waves done reading sB
            // epilogue L0: channels -> sB
            #pragma unroll
            for (int g = 0; g < 4; ++g) {       // reg-groups: j = j0g + (r&3)
                const int j0g = mw * 32 + 8 * g + 4 * kh;
                const v4f bb = *(const v4f*)&b1[j0g];
                float chv[NC][4];               // [c][r]
                #pragma unroll
                for (int r = 0; r < 4; ++r) {
                    float z = acc[0][g * 4 + r] + bb[r];
                    float a = fast_tanh(z);
                    chv[0][r] = a;
                    if (NC == 4) {
                        float t = fmaf(-a, a, 1.0f);
                        float zx = acc[1][g * 4 + r], zy = acc[2][g * 4 + r],
                              zl = acc[3][g * 4 + r];
                        float s2 = fmaf(zx, zx, zy * zy);
                        chv[1][r] = t * zx;
                        chv[2][r] = t * zy;
                        chv[3][r] = fmaf(t, zl, -2.0f * a * t * s2);
                    }
                }
                #pragma unroll
                for (int c = 0; c < NC; ++c) {
                    const int row = (c * 32 + l31) * KP + j0g;
                    *(uint2*)&sBh[row] = pk4(chv[c]);
                }
            }
            __syncthreads();
        }
    }

    // ---- fused readout on the L=1 acc: chain + W3 dot entirely in registers
    //      (W dbuf dead here -> fits the register budget; writes only sPart) ----
    {
        float part = 0.0f;
        #pragma unroll
        for (int g = 0; g < 4; ++g) {
            const int j0g = mw * 32 + 8 * g + 4 * kh;
            const v4f bb = *(const v4f*)&b2[j0g];
            const v4f w3 = *(const v4f*)&W3[j0g];
            #pragma unroll
            for (int r = 0; r < 4; ++r) {
                float z = acc[0][g * 4 + r] + bb[r];
                float a = fast_tanh(z);
                float v;
                if (NC == 1) {
                    v = a;                              // pred = a . W3
                } else {
                    float t = fmaf(-a, a, 1.0f);
                    float zx = acc[1][g * 4 + r], zy = acc[2][g * 4 + r],
                          zl = acc[3][g * 4 + r];
                    float s2 = fmaf(zx, zx, zy * zy);
                    v = t * fmaf(-2.0f * a, s2, zl);    // pred = lap . W3
                }
                part = fmaf(v, w3[r], part);
            }
        }
        part += __shfl_xor(part, 32, 64);       // combine the two kh halves
        if (kh == 0) sPart[mw * 32 + l31] = part;
        __syncthreads();
        if (mw == 0) {                          // wave 0: combine 4 m-tiles/point
            const int p = l31;
            float pred = (sPart[p] + sPart[32 + p]) + (sPart[64 + p] + sPart[96 + p])
                       + ((NC == 1) ? b3[0] : 0.0f);    // lap kills b3
            float d = pred - tgt[pbase + p];
            float sq = (kh == 0) ? d * d : 0.0f;
            sq += __shfl_xor(sq, 1, 64);
            sq += __shfl_xor(sq, 2, 64);
            sq += __shfl_xor(sq, 4, 64);
            sq += __shfl_xor(sq, 8, 64);
            sq += __shfl_xor(sq, 16, 64);
            sq += __shfl_xor(sq, 32, 64);
            if (lane == 0) atomicAdd(out_slot, sq * scale);
        }
    }
}

// Fused interior+boundary: ONE uniform branch at entry (coarse-grain diamond),
// each side a clean straight-line template instantiation.
__global__ __launch_bounds__(256, 4) void pinn_mfma_kernel(
    const float* __restrict__ xy_int, const float* __restrict__ f_t,
    const float* __restrict__ xy_bd, const float* __restrict__ g_t,
    const float* __restrict__ W0, const float* __restrict__ b0,
    const float* __restrict__ b1, const float* __restrict__ b2,
    const float* __restrict__ W3, const float* __restrict__ b3,
    const unsigned short* __restrict__ ws, float* __restrict__ out,
    int gi, float scale_int, float scale_bd)
{
    extern __shared__ char smem_raw[];
    unsigned short* sBh = (unsigned short*)smem_raw;     // [4*32][KP] bf16 (RNE)
    float* sPart = (float*)(sBh + 4 * 32 * KP);          // [128] per-(mw,p) partials

    const int b = (int)blockIdx.x;
    if (b >= gi)
        run_pinn<1>(xy_bd, g_t, W0, b0, b1, b2, W3, b3, ws,
                    out + 0, scale_bd, (b - gi) * PTS, sBh, sPart);
    else
        run_pinn<4>(xy_int, f_t, W0, b0, b1, b2, W3, b3, ws,
                    out + 1, scale_int, b * PTS, sBh, sPart);
}

extern "C" void kernel_launch(void* const* d_in, const int* in_sizes, int n_in,
                              void* d_out, int out_size, void* d_ws, size_t ws_size,
                              hipStream_t stream) {
    const float* xy_int = (const float*)d_in[0];
    const float* f      = (const float*)d_in[1];
    const float* xy_bd  = (const float*)d_in[2];
    const float* g      = (const float*)d_in[3];
    const float* W0 = (const float*)d_in[4];
    const float* b0 = (const float*)d_in[5];
    const float* W1 = (const float*)d_in[6];
    const float* b1 = (const float*)d_in[7];
    const float* W2 = (const float*)d_in[8];
    const float* b2 = (const float*)d_in[9];
    const float* W3 = (const float*)d_in[10];
    const float* b3 = (const float*)d_in[11];
    float* out = (float*)d_out;
    unsigned short* ws = (unsigned short*)d_ws;   // needs 256 KB

    const int n_int = in_sizes[0] / 2;   // 262144
    const int n_bd  = in_sizes[2] / 2;   // 16384

    prep_w_kernel<<<16, 256, 0, stream>>>(W1, W2, ws, out);

    const int smem = (4 * 32 * KP) * 2 + 128 * 4;  // 35,328 B -> 4 blocks/CU
    const int gi = n_int / PTS;
    const int gb = n_bd / PTS;

    pinn_mfma_kernel<<<gi + gb, 256, smem, stream>>>(
        xy_int, f, xy_bd, g, W0, b0, b1, b2, W3, b3, ws, out,
        gi, 0.5f / (float)n_int, 0.5f / (float)n_bd);
}

// Round 16
// 194.994 us; speedup vs baseline: 1.3052x; 1.0981x over previous
//
#include <hip/hip_runtime.h>

#define HID 128
#define PTS 32
#define KP  136   // sB k-row stride in bf16 units (128 + 8 pad; rows 272B = 16B-aligned)
#define FRAGS_PER_W 2048           // 4 mw * 8 ks8 * 64 lanes
#define WS_ELEMS (FRAGS_PER_W * 8) // ushorts per weight plane

typedef float v4f  __attribute__((ext_vector_type(4)));
typedef float v16f __attribute__((ext_vector_type(16)));
typedef short s8v  __attribute__((ext_vector_type(8)));         // 8 bf16 (MFMA A/B frag)

__device__ __forceinline__ unsigned short f2bf(float f) {       // RNE (prep only)
    unsigned u = __builtin_bit_cast(unsigned, f);
    u = (u + 0x7FFFu + ((u >> 16) & 1u)) >> 16;
    return (unsigned short)u;
}

// --- packed fp32 -> 2x bf16 (RNE), 1 instr on gfx950 ---
#if __has_builtin(__builtin_amdgcn_cvt_pk_bf16_f32)
typedef __bf16 bf16x2 __attribute__((ext_vector_type(2)));
__device__ __forceinline__ unsigned pk2(float f0, float f1) {   // (bf(f1)<<16)|bf(f0)
    return __builtin_bit_cast(unsigned, __builtin_amdgcn_cvt_pk_bf16_f32(f0, f1));
}
#else
__device__ __forceinline__ unsigned pk2(float f0, float f1) {
    unsigned u0 = __builtin_bit_cast(unsigned, f0);
    unsigned u1 = __builtin_bit_cast(unsigned, f1);
    u0 += 0x7FFFu + ((u0 >> 16) & 1u);
    u1 += 0x7FFFu + ((u1 >> 16) & 1u);
    return __builtin_amdgcn_perm(u1, u0, 0x07060302u);
}
#endif
__device__ __forceinline__ uint2 pk4(const float* f) {
    uint2 h;
    h.x = pk2(f[0], f[1]);
    h.y = pk2(f[2], f[3]);
    return h;
}

// tanh(x) = 1 - 2/(exp(2x)+1); single mul + v_exp + v_rcp
__device__ __forceinline__ float fast_tanh(float x) {
#if __has_builtin(__builtin_amdgcn_exp2f)
    float e = __builtin_amdgcn_exp2f(x * 2.885390081777927f);   // 2*log2(e)
#else
    float e = __expf(2.0f * x);
#endif
    float r = __builtin_amdgcn_rcpf(e + 1.0f);
    return 1.0f - 2.0f * r;
}

// One-time: W1/W2 -> RNE bf16 A-fragments for 32x32x16, frag-linear in d_ws.
// A[m][k] = W[k][m]; m = mw*32 + (lane&31), k = ks8*16 + (lane>>5)*8 + i.
// frag idx r = mw*512 + ks8*64 + lane. Planes: [W1][W2] (single plane each:
// round 16 drops the lo-residual product -- RNE bf16 weights, like activations).
__global__ __launch_bounds__(256) void prep_w_kernel(
    const float* __restrict__ W1, const float* __restrict__ W2,
    unsigned short* __restrict__ ws, float* __restrict__ out)
{
    if (blockIdx.x == 0 && threadIdx.x < 2) out[threadIdx.x] = 0.0f;
    const int t = blockIdx.x * 256 + threadIdx.x;   // 0..4095
    const int w = t >> 11;
    const int r = t & 2047;
    const int mw = r >> 9;
    const int ks8 = (r >> 6) & 7;
    const int lane = r & 63;
    const int m = mw * 32 + (lane & 31);
    const int kb = ks8 * 16 + (lane >> 5) * 8;
    const float* W = w ? W2 : W1;
    s8v hv;
    #pragma unroll
    for (int i = 0; i < 8; ++i)
        hv[i] = (short)f2bf(W[(kb + i) * HID + m]);
    *(s8v*)&ws[((size_t)w * FRAGS_PER_W + r) * 8] = hv;
}

// Round-15 body (proven 143.5us, VGPR 64, no spill) with the W-lo product
// DROPPED: weights are plain RNE bf16 (same precision class as the activations,
// whose rounding already washes out below the loss reporting floor). Halves
// MFMA work (55->27us busy), W L2 traffic, and W registers (16 VGPR freed).
// FALLBACK: round-15 source if absmax exceeds threshold.
// LESSON (r13): uniform branches COARSE-GRAIN only (template dispatch at entry).
// NC=4: interior (lap readout). NC=1: boundary (value only).
// Wave = m-tile mw (32 j) x all n-tiles (==channels). C/D (m101, verified):
// col=lane&31 (=p), row=(reg&3)+8*(reg>>2)+4*(lane>>5) (=j offset).
template <int NC>
__device__ __forceinline__ void run_pinn(
    const float* __restrict__ xy, const float* __restrict__ tgt,
    const float* __restrict__ W0, const float* __restrict__ b0,
    const float* __restrict__ b1, const float* __restrict__ b2,
    const float* __restrict__ W3, const float* __restrict__ b3,
    const unsigned short* __restrict__ ws, float* __restrict__ out_slot,
    float scale, int pbase, unsigned short* sBh, float* sPart)
{
    const int tid  = threadIdx.x;
    const int lane = tid & 63;
    const int mw   = tid >> 6;      // wave = m-tile (32 j-rows)
    const int l31  = lane & 31;
    const int kh   = lane >> 5;     // k-half of frag / +4*kh j-offset in C

    // ---- layer 0: 2 -> 128, VALU, RNE-bf16 store into sB ----
    {
        const int tj = tid & 31, tp = tid >> 5;
        const int j0 = tj * 4, p0 = tp * 4;
        float wx[4], wy[4], bb[4];
        #pragma unroll
        for (int jj = 0; jj < 4; ++jj) {
            wx[jj] = W0[j0 + jj];
            wy[jj] = W0[HID + j0 + jj];
            bb[jj] = b0[j0 + jj];
        }
        #pragma unroll
        for (int pp = 0; pp < 4; ++pp) {
            const int p = p0 + pp;
            const float2 t2 = ((const float2*)xy)[pbase + p];
            float chv[NC][4];                   // [c][jj]
            #pragma unroll
            for (int jj = 0; jj < 4; ++jj) {
                float z = fmaf(t2.x, wx[jj], fmaf(t2.y, wy[jj], bb[jj]));
                float a = fast_tanh(z);
                chv[0][jj] = a;
                if (NC == 4) {
                    float t = fmaf(-a, a, 1.0f);
                    float s2 = fmaf(wx[jj], wx[jj], wy[jj] * wy[jj]);
                    chv[1][jj] = t * wx[jj];
                    chv[2][jj] = t * wy[jj];
                    chv[3][jj] = -2.0f * a * t * s2;    // z_lap = 0 at layer 0
                }
            }
            #pragma unroll
            for (int c = 0; c < NC; ++c) {
                const int row = (c * 32 + p) * KP + j0;
                *(uint2*)&sBh[row] = pk4(chv[c]);
            }
        }
    }
    __syncthreads();

    v16f acc[NC];   // [ntile == channel]

    // ---- hidden layers: D = W(A-op 32x32, bf16) x Act(B-op), 1 product ----
    #pragma unroll
    for (int L = 0; L < 2; ++L) {
        const unsigned short* wsp = ws + (size_t)L * WS_ELEMS;

        // stage = K32 = 2 ks8 sub-frags; double-buffered: 4 s8v = 16 VGPR
        s8v whi[2][2];
        #pragma unroll
        for (int h = 0; h < 2; ++h) {
            const int idx = mw * 512 + h * 64 + lane;         // stage 0
            whi[0][h] = *(const s8v*)&wsp[(size_t)idx * 8];
        }

        #pragma unroll
        for (int nt = 0; nt < NC; ++nt) acc[nt] = (v16f)0.0f;

        #pragma unroll
        for (int s = 0; s < 4; ++s) {
            const int cur = s & 1, nxt = cur ^ 1;
            if (s < 3) {    // prefetch next stage from L2 while MFMAs run
                #pragma unroll
                for (int h = 0; h < 2; ++h) {
                    const int idx = mw * 512 + ((s + 1) * 2 + h) * 64 + lane;
                    whi[nxt][h] = *(const s8v*)&wsp[(size_t)idx * 8];
                }
            }
            #pragma unroll
            for (int h = 0; h < 2; ++h) {
                const int koff = (s * 2 + h) * 16 + kh * 8;   // B: k=(lane>>5)*8+i
                #pragma unroll
                for (int nt = 0; nt < NC; ++nt) {
                    s8v bh = *(const s8v*)&sBh[(nt * 32 + l31) * KP + koff];
                    acc[nt] = __builtin_amdgcn_mfma_f32_32x32x16_bf16(
                        whi[cur][h], bh, acc[nt], 0, 0, 0);
                }
            }
        }

        if (L == 0) {
            __syncthreads();        // all waves done reading sB
            // epilogue L0: channels -> sB
            #pragma unroll
            for (int g = 0; g < 4; ++g) {       // reg-groups: j = j0g + (r&3)
                const int j0g = mw * 32 + 8 * g + 4 * kh;
                const v4f bb = *(const v4f*)&b1[j0g];
                float chv[NC][4];               // [c][r]
                #pragma unroll
                for (int r = 0; r < 4; ++r) {
                    float z = acc[0][g * 4 + r] + bb[r];
                    float a = fast_tanh(z);
                    chv[0][r] = a;
                    if (NC == 4) {
                        float t = fmaf(-a, a, 1.0f);
                        float zx = acc[1][g * 4 + r], zy = acc[2][g * 4 + r],
                              zl = acc[3][g * 4 + r];
                        float s2 = fmaf(zx, zx, zy * zy);
                        chv[1][r] = t * zx;
                        chv[2][r] = t * zy;
                        chv[3][r] = fmaf(t, zl, -2.0f * a * t * s2);
                    }
                }
                #pragma unroll
                for (int c = 0; c < NC; ++c) {
                    const int row = (c * 32 + l31) * KP + j0g;
                    *(uint2*)&sBh[row] = pk4(chv[c]);
                }
            }
            __syncthreads();
        }
    }

    // ---- fused readout on the L=1 acc: chain + W3 dot entirely in registers ----
    {
        float part = 0.0f;
        #pragma unroll
        for (int g = 0; g < 4; ++g) {
            const int j0g = mw * 32 + 8 * g + 4 * kh;
            const v4f bb = *(const v4f*)&b2[j0g];
            const v4f w3 = *(const v4f*)&W3[j0g];
            #pragma unroll
            for (int r = 0; r < 4; ++r) {
                float z = acc[0][g * 4 + r] + bb[r];
                float a = fast_tanh(z);
                float v;
                if (NC == 1) {
                    v = a;                              // pred = a . W3
                } else {
                    float t = fmaf(-a, a, 1.0f);
                    float zx = acc[1][g * 4 + r], zy = acc[2][g * 4 + r],
                          zl = acc[3][g * 4 + r];
                    float s2 = fmaf(zx, zx, zy * zy);
                    v = t * fmaf(-2.0f * a, s2, zl);    // pred = lap . W3
                }
                part = fmaf(v, w3[r], part);
            }
        }
        part += __shfl_xor(part, 32, 64);       // combine the two kh halves
        if (kh == 0) sPart[mw * 32 + l31] = part;
        __syncthreads();
        if (mw == 0) {                          // wave 0: combine 4 m-tiles/point
            const int p = l31;
            float pred = (sPart[p] + sPart[32 + p]) + (sPart[64 + p] + sPart[96 + p])
                       + ((NC == 1) ? b3[0] : 0.0f);    // lap kills b3
            float d = pred - tgt[pbase + p];
            float sq = (kh == 0) ? d * d : 0.0f;
            sq += __shfl_xor(sq, 1, 64);
            sq += __shfl_xor(sq, 2, 64);
            sq += __shfl_xor(sq, 4, 64);
            sq += __shfl_xor(sq, 8, 64);
            sq += __shfl_xor(sq, 16, 64);
            sq += __shfl_xor(sq, 32, 64);
            if (lane == 0) atomicAdd(out_slot, sq * scale);
        }
    }
}

// Fused interior+boundary: ONE uniform branch at entry (coarse-grain diamond),
// each side a clean straight-line template instantiation.
__global__ __launch_bounds__(256, 4) void pinn_mfma_kernel(
    const float* __restrict__ xy_int, const float* __restrict__ f_t,
    const float* __restrict__ xy_bd, const float* __restrict__ g_t,
    const float* __restrict__ W0, const float* __restrict__ b0,
    const float* __restrict__ b1, const float* __restrict__ b2,
    const float* __restrict__ W3, const float* __restrict__ b3,
    const unsigned short* __restrict__ ws, float* __restrict__ out,
    int gi, float scale_int, float scale_bd)
{
    extern __shared__ char smem_raw[];
    unsigned short* sBh = (unsigned short*)smem_raw;     // [4*32][KP] bf16 (RNE)
    float* sPart = (float*)(sBh + 4 * 32 * KP);          // [128] per-(mw,p) partials

    const int b = (int)blockIdx.x;
    if (b >= gi)
        run_pinn<1>(xy_bd, g_t, W0, b0, b1, b2, W3, b3, ws,
                    out + 0, scale_bd, (b - gi) * PTS, sBh, sPart);
    else
        run_pinn<4>(xy_int, f_t, W0, b0, b1, b2, W3, b3, ws,
                    out + 1, scale_int, b * PTS, sBh, sPart);
}

extern "C" void kernel_launch(void* const* d_in, const int* in_sizes, int n_in,
                              void* d_out, int out_size, void* d_ws, size_t ws_size,
                              hipStream_t stream) {
    const float* xy_int = (const float*)d_in[0];
    const float* f      = (const float*)d_in[1];
    const float* xy_bd  = (const float*)d_in[2];
    const float* g      = (const float*)d_in[3];
    const float* W0 = (const float*)d_in[4];
    const float* b0 = (const float*)d_in[5];
    const float* W1 = (const float*)d_in[6];
    const float* b1 = (const float*)d_in[7];
    const float* W2 = (const float*)d_in[8];
    const float* b2 = (const float*)d_in[9];
    const float* W3 = (const float*)d_in[10];
    const float* b3 = (const float*)d_in[11];
    float* out = (float*)d_out;
    unsigned short* ws = (unsigned short*)d_ws;   // needs 128 KB

    const int n_int = in_sizes[0] / 2;   // 262144
    const int n_bd  = in_sizes[2] / 2;   // 16384

    prep_w_kernel<<<16, 256, 0, stream>>>(W1, W2, ws, out);

    const int smem = (4 * 32 * KP) * 2 + 128 * 4;  // 35,328 B -> 4 blocks/CU
    const int gi = n_int / PTS;
    const int gb = n_bd / PTS;

    pinn_mfma_kernel<<<gi + gb, 256, smem, stream>>>(
        xy_int, f, xy_bd, g, W0, b0, b1, b2, W3, b3, ws, out,
        gi, 0.5f / (float)n_int, 0.5f / (float)n_bd);
}

// Round 17
// 194.362 us; speedup vs baseline: 1.3095x; 1.0033x over previous
//
#include <hip/hip_runtime.h>

#define HID 128
#define PTS 32
#define KP  136   // sB k-row stride in bf16 units (128 + 8 pad; rows 272B = 16B-aligned)
#define FRAGS_PER_W 2048           // 4 mw * 8 ks8 * 64 lanes
#define WS_ELEMS (FRAGS_PER_W * 8) // ushorts per weight plane

typedef float v4f  __attribute__((ext_vector_type(4)));
typedef float v16f __attribute__((ext_vector_type(16)));
typedef short s8v  __attribute__((ext_vector_type(8)));         // 8 bf16 (MFMA A/B frag)

__device__ __forceinline__ unsigned short f2bf(float f) {       // RNE (prep only)
    unsigned u = __builtin_bit_cast(unsigned, f);
    u = (u + 0x7FFFu + ((u >> 16) & 1u)) >> 16;
    return (unsigned short)u;
}

// --- packed fp32 -> 2x bf16 (RNE), 1 instr on gfx950 ---
#if __has_builtin(__builtin_amdgcn_cvt_pk_bf16_f32)
typedef __bf16 bf16x2 __attribute__((ext_vector_type(2)));
__device__ __forceinline__ unsigned pk2(float f0, float f1) {   // (bf(f1)<<16)|bf(f0)
    return __builtin_bit_cast(unsigned, __builtin_amdgcn_cvt_pk_bf16_f32(f0, f1));
}
#else
__device__ __forceinline__ unsigned pk2(float f0, float f1) {
    unsigned u0 = __builtin_bit_cast(unsigned, f0);
    unsigned u1 = __builtin_bit_cast(unsigned, f1);
    u0 += 0x7FFFu + ((u0 >> 16) & 1u);
    u1 += 0x7FFFu + ((u1 >> 16) & 1u);
    return __builtin_amdgcn_perm(u1, u0, 0x07060302u);
}
#endif
__device__ __forceinline__ uint2 pk4(const float* f) {
    uint2 h;
    h.x = pk2(f[0], f[1]);
    h.y = pk2(f[2], f[3]);
    return h;
}

// tanh(x) = 1 - 2/(exp(2x)+1); single mul + v_exp + v_rcp
__device__ __forceinline__ float fast_tanh(float x) {
#if __has_builtin(__builtin_amdgcn_exp2f)
    float e = __builtin_amdgcn_exp2f(x * 2.885390081777927f);   // 2*log2(e)
#else
    float e = __expf(2.0f * x);
#endif
    float r = __builtin_amdgcn_rcpf(e + 1.0f);
    return 1.0f - 2.0f * r;
}

// One-time: W1/W2 -> RNE bf16 A-fragments for 32x32x16, frag-linear in d_ws.
// A[m][k] = W[k][m]; m = mw*32 + (lane&31), k = ks8*16 + (lane>>5)*8 + i.
// frag idx r = mw*512 + ks8*64 + lane. Planes: [W1][W2].
__global__ __launch_bounds__(256) void prep_w_kernel(
    const float* __restrict__ W1, const float* __restrict__ W2,
    unsigned short* __restrict__ ws, float* __restrict__ out)
{
    if (blockIdx.x == 0 && threadIdx.x < 2) out[threadIdx.x] = 0.0f;
    const int t = blockIdx.x * 256 + threadIdx.x;   // 0..4095
    const int w = t >> 11;
    const int r = t & 2047;
    const int mw = r >> 9;
    const int ks8 = (r >> 6) & 7;
    const int lane = r & 63;
    const int m = mw * 32 + (lane & 31);
    const int kb = ks8 * 16 + (lane >> 5) * 8;
    const float* W = w ? W2 : W1;
    s8v hv;
    #pragma unroll
    for (int i = 0; i < 8; ++i)
        hv[i] = (short)f2bf(W[(kb + i) * HID + m]);
    *(s8v*)&ws[((size_t)w * FRAGS_PER_W + r) * 8] = hv;
}

// Round-16 body (proven 122.3us, VGPR 64, no spill) with the ks-stage W
// double-buffer DELETED: single-plane bf16 weights mean a whole layer's W is
// 8 s8v = 32 VGPR, loaded in one burst at layer start (latency paid once,
// hidden by 16 waves/CU), leaving a pure LDS+MFMA inner loop with no in-loop
// VMEM waits. The dbuf was sized for 2 products; with 1 product its 8-MFMA
// stages couldn't cover L2 latency and CREATED the stage-boundary stalls.
// LESSON (r13): uniform branches COARSE-GRAIN only (template dispatch at entry).
// NC=4: interior (lap readout). NC=1: boundary (value only).
// Wave = m-tile mw (32 j) x all n-tiles (==channels). C/D (m101, verified):
// col=lane&31 (=p), row=(reg&3)+8*(reg>>2)+4*(lane>>5) (=j offset).
template <int NC>
__device__ __forceinline__ void run_pinn(
    const float* __restrict__ xy, const float* __restrict__ tgt,
    const float* __restrict__ W0, const float* __restrict__ b0,
    const float* __restrict__ b1, const float* __restrict__ b2,
    const float* __restrict__ W3, const float* __restrict__ b3,
    const unsigned short* __restrict__ ws, float* __restrict__ out_slot,
    float scale, int pbase, unsigned short* sBh, float* sPart)
{
    const int tid  = threadIdx.x;
    const int lane = tid & 63;
    const int mw   = tid >> 6;      // wave = m-tile (32 j-rows)
    const int l31  = lane & 31;
    const int kh   = lane >> 5;     // k-half of frag / +4*kh j-offset in C

    // ---- layer 0: 2 -> 128, VALU, RNE-bf16 store into sB ----
    {
        const int tj = tid & 31, tp = tid >> 5;
        const int j0 = tj * 4, p0 = tp * 4;
        float wx[4], wy[4], bb[4], m2s2[4];
        #pragma unroll
        for (int jj = 0; jj < 4; ++jj) {
            wx[jj] = W0[j0 + jj];
            wy[jj] = W0[HID + j0 + jj];
            bb[jj] = b0[j0 + jj];
            m2s2[jj] = -2.0f * fmaf(wx[jj], wx[jj], wy[jj] * wy[jj]);
        }
        #pragma unroll
        for (int pp = 0; pp < 4; ++pp) {
            const int p = p0 + pp;
            const float2 t2 = ((const float2*)xy)[pbase + p];
            float chv[NC][4];                   // [c][jj]
            #pragma unroll
            for (int jj = 0; jj < 4; ++jj) {
                float z = fmaf(t2.x, wx[jj], fmaf(t2.y, wy[jj], bb[jj]));
                float a = fast_tanh(z);
                chv[0][jj] = a;
                if (NC == 4) {
                    float t = fmaf(-a, a, 1.0f);
                    chv[1][jj] = t * wx[jj];
                    chv[2][jj] = t * wy[jj];
                    chv[3][jj] = (a * t) * m2s2[jj];    // z_lap = 0 at layer 0
                }
            }
            #pragma unroll
            for (int c = 0; c < NC; ++c) {
                const int row = (c * 32 + p) * KP + j0;
                *(uint2*)&sBh[row] = pk4(chv[c]);
            }
        }
    }
    __syncthreads();

    v16f acc[NC];   // [ntile == channel]

    // ---- hidden layers: D = W(A-op 32x32, bf16) x Act(B-op), 1 product ----
    #pragma unroll
    for (int L = 0; L < 2; ++L) {
        const unsigned short* wsp = ws + (size_t)L * WS_ELEMS;

        // full layer W resident: 8 s8v = 32 VGPR, one load burst, no dbuf
        s8v wf[8];
        #pragma unroll
        for (int q = 0; q < 8; ++q)
            wf[q] = *(const s8v*)&wsp[(size_t)(mw * 512 + q * 64 + lane) * 8];

        #pragma unroll
        for (int nt = 0; nt < NC; ++nt) acc[nt] = (v16f)0.0f;

        #pragma unroll
        for (int q = 0; q < 8; ++q) {           // q == ks8 (16-wide k-block)
            const int koff = q * 16 + kh * 8;   // B: k=(lane>>5)*8+i
            #pragma unroll
            for (int nt = 0; nt < NC; ++nt) {
                s8v bh = *(const s8v*)&sBh[(nt * 32 + l31) * KP + koff];
                acc[nt] = __builtin_amdgcn_mfma_f32_32x32x16_bf16(
                    wf[q], bh, acc[nt], 0, 0, 0);
            }
        }

        if (L == 0) {
            __syncthreads();        // all waves done reading sB
            // epilogue L0: channels -> sB
            #pragma unroll
            for (int g = 0; g < 4; ++g) {       // reg-groups: j = j0g + (r&3)
                const int j0g = mw * 32 + 8 * g + 4 * kh;
                const v4f bb = *(const v4f*)&b1[j0g];
                float chv[NC][4];               // [c][r]
                #pragma unroll
                for (int r = 0; r < 4; ++r) {
                    float z = acc[0][g * 4 + r] + bb[r];
                    float a = fast_tanh(z);
                    chv[0][r] = a;
                    if (NC == 4) {
                        float t = fmaf(-a, a, 1.0f);
                        float zx = acc[1][g * 4 + r], zy = acc[2][g * 4 + r],
                              zl = acc[3][g * 4 + r];
                        float s2 = fmaf(zx, zx, zy * zy);
                        float u  = fmaf(-(a + a), s2, zl);
                        chv[1][r] = t * zx;
                        chv[2][r] = t * zy;
                        chv[3][r] = t * u;
                    }
                }
                #pragma unroll
                for (int c = 0; c < NC; ++c) {
                    const int row = (c * 32 + l31) * KP + j0g;
                    *(uint2*)&sBh[row] = pk4(chv[c]);
                }
            }
            __syncthreads();
        }
    }

    // ---- fused readout on the L=1 acc: chain + W3 dot entirely in registers ----
    {
        float part = 0.0f;
        #pragma unroll
        for (int g = 0; g < 4; ++g) {
            const int j0g = mw * 32 + 8 * g + 4 * kh;
            const v4f bb = *(const v4f*)&b2[j0g];
            const v4f w3 = *(const v4f*)&W3[j0g];
            #pragma unroll
            for (int r = 0; r < 4; ++r) {
                float z = acc[0][g * 4 + r] + bb[r];
                float a = fast_tanh(z);
                float v;
                if (NC == 1) {
                    v = a;                              // pred = a . W3
                } else {
                    float t = fmaf(-a, a, 1.0f);
                    float zx = acc[1][g * 4 + r], zy = acc[2][g * 4 + r],
                          zl = acc[3][g * 4 + r];
                    float s2 = fmaf(zx, zx, zy * zy);
                    v = t * fmaf(-(a + a), s2, zl);     // pred = lap . W3
                }
                part = fmaf(v, w3[r], part);
            }
        }
        part += __shfl_xor(part, 32, 64);       // combine the two kh halves
        if (kh == 0) sPart[mw * 32 + l31] = part;
        __syncthreads();
        if (mw == 0) {                          // wave 0: combine 4 m-tiles/point
            const int p = l31;
            float pred = (sPart[p] + sPart[32 + p]) + (sPart[64 + p] + sPart[96 + p])
                       + ((NC == 1) ? b3[0] : 0.0f);    // lap kills b3
            float d = pred - tgt[pbase + p];
            float sq = (kh == 0) ? d * d : 0.0f;
            sq += __shfl_xor(sq, 1, 64);
            sq += __shfl_xor(sq, 2, 64);
            sq += __shfl_xor(sq, 4, 64);
            sq += __shfl_xor(sq, 8, 64);
            sq += __shfl_xor(sq, 16, 64);
            sq += __shfl_xor(sq, 32, 64);
            if (lane == 0) atomicAdd(out_slot, sq * scale);
        }
    }
}

// Fused interior+boundary: ONE uniform branch at entry (coarse-grain diamond),
// each side a clean straight-line template instantiation.
__global__ __launch_bounds__(256, 4) void pinn_mfma_kernel(
    const float* __restrict__ xy_int, const float* __restrict__ f_t,
    const float* __restrict__ xy_bd, const float* __restrict__ g_t,
    const float* __restrict__ W0, const float* __restrict__ b0,
    const float* __restrict__ b1, const float* __restrict__ b2,
    const float* __restrict__ W3, const float* __restrict__ b3,
    const unsigned short* __restrict__ ws, float* __restrict__ out,
    int gi, float scale_int, float scale_bd)
{
    extern __shared__ char smem_raw[];
    unsigned short* sBh = (unsigned short*)smem_raw;     // [4*32][KP] bf16 (RNE)
    float* sPart = (float*)(sBh + 4 * 32 * KP);          // [128] per-(mw,p) partials

    const int b = (int)blockIdx.x;
    if (b >= gi)
        run_pinn<1>(xy_bd, g_t, W0, b0, b1, b2, W3, b3, ws,
                    out + 0, scale_bd, (b - gi) * PTS, sBh, sPart);
    else
        run_pinn<4>(xy_int, f_t, W0, b0, b1, b2, W3, b3, ws,
                    out + 1, scale_int, b * PTS, sBh, sPart);
}

extern "C" void kernel_launch(void* const* d_in, const int* in_sizes, int n_in,
                              void* d_out, int out_size, void* d_ws, size_t ws_size,
                              hipStream_t stream) {
    const float* xy_int = (const float*)d_in[0];
    const float* f      = (const float*)d_in[1];
    const float* xy_bd  = (const float*)d_in[2];
    const float* g      = (const float*)d_in[3];
    const float* W0 = (const float*)d_in[4];
    const float* b0 = (const float*)d_in[5];
    const float* W1 = (const float*)d_in[6];
    const float* b1 = (const float*)d_in[7];
    const float* W2 = (const float*)d_in[8];
    const float* b2 = (const float*)d_in[9];
    const float* W3 = (const float*)d_in[10];
    const float* b3 = (const float*)d_in[11];
    float* out = (float*)d_out;
    unsigned short* ws = (unsigned short*)d_ws;   // needs 128 KB

    const int n_int = in_sizes[0] / 2;   // 262144
    const int n_bd  = in_sizes[2] / 2;   // 16384

    prep_w_kernel<<<16, 256, 0, stream>>>(W1, W2, ws, out);

    const int smem = (4 * 32 * KP) * 2 + 128 * 4;  // 35,328 B -> 4 blocks/CU
    const int gi = n_int / PTS;
    const int gb = n_bd / PTS;

    pinn_mfma_kernel<<<gi + gb, 256, smem, stream>>>(
        xy_int, f, xy_bd, g, W0, b0, b1, b2, W3, b3, ws, out,
        gi, 0.5f / (float)n_int, 0.5f / (float)n_bd);
}